// Round 3
// baseline (113.519 us; speedup 1.0000x reference)
//
#include <hip/hip_runtime.h>

// Problem dims (fixed by reference): B=32, S=64, E=256, H=4, D=64
constexpr int ED = 256;    // embedding dim

typedef _Float16 half8 __attribute__((ext_vector_type(8)));
typedef float floatx4 __attribute__((ext_vector_type(4)));

__device__ inline unsigned short f2h(float f) {   // fp32 -> fp16 bits (RNE)
  union { _Float16 h; unsigned short u; } c;
  c.h = (_Float16)f;
  return c.u;
}

// ---------------------------------------------------------------------------
// Kernel A (prep): B-fragment-swizzled fp16 exp(W) for all 4 weight matrices.
// B[k][n] = exp(W[n][k]); frag layout for mfma_f32_16x16x32 (lane l:
// n = l&15, k = 32*kk + 8*(l>>4) + jj): ushort idx = (kk*256+n)*32 + kl.
// grid (32,4), block 256.
// ---------------------------------------------------------------------------
__global__ __launch_bounds__(256) void expT_swz_kernel(
    const float* __restrict__ Wq, const float* __restrict__ Wk,
    const float* __restrict__ Wv, const float* __restrict__ Wo,
    unsigned short* __restrict__ EqS, unsigned short* __restrict__ EkS,
    unsigned short* __restrict__ EvS, unsigned short* __restrict__ EoS)
{
  int z = blockIdx.y;
  const float* W = (z == 0) ? Wq : (z == 1) ? Wk : (z == 2) ? Wv : Wo;
  unsigned short* out = (z == 0) ? EqS : (z == 1) ? EkS : (z == 2) ? EvS : EoS;
  int t = threadIdx.x;
  int n = blockIdx.x * 8 + (t >> 5), kl = t & 31;
#pragma unroll
  for (int kk = 0; kk < 8; ++kk)
    out[(kk * 256 + n) * 32 + kl] = f2h(__expf(W[n * ED + 32 * kk + kl]));
}

// ---------------------------------------------------------------------------
// Kernel B (fused): one block per batch (32 blocks x 512 threads = 8 waves).
// Per block: stage-x -> qkv MFMA -> softmax(q+k)/v epilogue (in C-frag
// layout, no fbuf) -> attn@v MFMA -> cross-wave rowmax -> exp -> o-linear
// MFMA -> log epilogue -> y. All intermediates in LDS; no AS/VS/XS global
// round-trips.
// LDS: xoswz (32K, xswz early / oswz late — reuse is sync-separated),
//      aswz (32K), vswz (32K), Mrow/pmax/Omax (~2.5K) = ~98.6 KB, 1 blk/CU.
// Wave roles: qkv & o-linear: (mt = w>>1, hf = w&1) -> 16 rows x 128 cols.
//             attn@v:        (hd = w>>1, nh = w&1) -> head hd, 32 e-cols.
// ---------------------------------------------------------------------------
__global__ __launch_bounds__(512, 1) void fused_attn_kernel(
    const float* __restrict__ x,
    const unsigned short* __restrict__ EqS, const unsigned short* __restrict__ EkS,
    const unsigned short* __restrict__ EvS, const unsigned short* __restrict__ EoS,
    const float* __restrict__ bq, const float* __restrict__ bk,
    const float* __restrict__ bv, const float* __restrict__ bo,
    float* __restrict__ y)
{
  int t = threadIdx.x, w = t >> 6, lane = t & 63;
  int b = blockIdx.x;
  int q = lane >> 4, nl = lane & 15;
  int rb = q * 4;

  __shared__ unsigned short xoswz[4][4096];  // 32K: xswz (per mt), later oswz
  __shared__ unsigned short aswz[4][4096];   // 32K: per head attn A-frags
  __shared__ unsigned short vswz[4][4096];   // 32K: per head v B-frags
  __shared__ float Mrow[64];
  __shared__ float pmax[8][64];
  __shared__ float Omax[64];

  // ---- stage x: wave w stages rows 8w..8w+7 as fp16 A-fragments ----
  float4 xv[8];
#pragma unroll
  for (int i = 0; i < 8; ++i)
    xv[i] = *(const float4*)&x[(size_t)(b * 64 + w * 8 + i) * ED + lane * 4];
#pragma unroll
  for (int i = 0; i < 8; ++i) {
    int r = w * 8 + i;
    float m = fmaxf(fmaxf(xv[i].x, xv[i].y), fmaxf(xv[i].z, xv[i].w));
#pragma unroll
    for (int off = 32; off > 0; off >>= 1) m = fmaxf(m, __shfl_xor(m, off));
    ushort4 pk;
    pk.x = f2h(__expf(xv[i].x - m));
    pk.y = f2h(__expf(xv[i].y - m));
    pk.z = f2h(__expf(xv[i].z - m));
    pk.w = f2h(__expf(xv[i].w - m));
    int k0 = lane * 4;                       // kk=k0>>5, q=(k0>>3)&3, jj=k0&7
    int idx = (k0 >> 5) * 512 + ((k0 >> 3) & 3) * 128 + (r & 15) * 8 + (k0 & 7);
    *(ushort4*)&xoswz[r >> 4][idx] = pk;
    if (lane == 0) Mrow[r] = m;
  }
  __syncthreads();

  // ---- qkv MFMA: wave = (mt, hf); 16 rows x 128 cols x 3 matrices ----
  int mt = w >> 1, hf = w & 1;
  const half8* XA = (const half8*)xoswz[mt];
  half8 af[8];
#pragma unroll
  for (int kk = 0; kk < 8; ++kk) af[kk] = XA[kk * 64 + lane];

  float Mr[4];
#pragma unroll
  for (int reg = 0; reg < 4; ++reg) Mr[reg] = Mrow[mt * 16 + rb + reg];

  float bqv[8], bkv[8], bvv[8];
#pragma unroll
  for (int nt = 0; nt < 8; ++nt) {
    int c = hf * 128 + nt * 16 + nl;
    bqv[nt] = bq[c]; bkv[nt] = bk[c]; bvv[nt] = bv[c];
  }

  const half8* BQ = (const half8*)EqS;
  const half8* BK = (const half8*)EkS;
  const half8* BV = (const half8*)EvS;
  floatx4 aq[8], ak[8], av[8];
#pragma unroll
  for (int nt = 0; nt < 8; ++nt) {
    aq[nt] = (floatx4){0.f, 0.f, 0.f, 0.f};
    ak[nt] = (floatx4){0.f, 0.f, 0.f, 0.f};
    av[nt] = (floatx4){0.f, 0.f, 0.f, 0.f};
  }
#pragma unroll
  for (int nt = 0; nt < 8; ++nt) {
    int n4 = (hf * 128 + nt * 16 + nl) * 4 + q;
#pragma unroll
    for (int kk = 0; kk < 8; ++kk) {
      aq[nt] = __builtin_amdgcn_mfma_f32_16x16x32_f16(af[kk], BQ[kk * 1024 + n4], aq[nt], 0, 0, 0);
      ak[nt] = __builtin_amdgcn_mfma_f32_16x16x32_f16(af[kk], BK[kk * 1024 + n4], ak[nt], 0, 0, 0);
      av[nt] = __builtin_amdgcn_mfma_f32_16x16x32_f16(af[kk], BV[kk * 1024 + n4], av[nt], 0, 0, 0);
    }
  }

  // ---- qkv epilogue directly in C-frag layout (row = mt*16+rb+reg,
  //      col = hf*128+nt*16+nl). v -> B-frag vswz; attn -> A-frag aswz. ----
#pragma unroll
  for (int nt = 0; nt < 8; ++nt) {
    int c = hf * 128 + nt * 16 + nl;
    int hd = c >> 6, n = c & 63;
#pragma unroll
    for (int reg = 0; reg < 4; ++reg) {
      int r = mt * 16 + rb + reg;        // k-index for attn@v B operand
      float vv = Mr[reg] + __logf(av[nt][reg]) + bvv[nt];
      vswz[hd][((r >> 5) * 64 + n) * 32 + ((r >> 3) & 3) * 8 + (r & 7)] = f2h(vv);
    }
  }
  // softmax(q+k) over each head's 64 cols: the 2*Mr term is constant per
  // row -> cancels in softmax, so s needs no rowmax constant.
#pragma unroll
  for (int hh = 0; hh < 2; ++hh) {
    int hd = hf * 2 + hh;
#pragma unroll
    for (int reg = 0; reg < 4; ++reg) {
      float s[4];
#pragma unroll
      for (int j = 0; j < 4; ++j) {
        int nt = hh * 4 + j;
        s[j] = __logf(aq[nt][reg]) + __logf(ak[nt][reg]) + bqv[nt] + bkv[nt];
      }
      float mm = fmaxf(fmaxf(s[0], s[1]), fmaxf(s[2], s[3]));
#pragma unroll
      for (int off = 8; off > 0; off >>= 1) mm = fmaxf(mm, __shfl_xor(mm, off));
      float ex[4], den = 0.f;
#pragma unroll
      for (int j = 0; j < 4; ++j) { ex[j] = __expf(s[j] - mm); den += ex[j]; }
#pragma unroll
      for (int off = 8; off > 0; off >>= 1) den += __shfl_xor(den, off);
      float rden = 1.0f / den;
#pragma unroll
      for (int j = 0; j < 4; ++j) {
        int d = j * 16 + nl;               // col within head
        aswz[hd][mt * 1024 + (d >> 5) * 512 + ((d >> 3) & 3) * 128
                 + (rb + reg) * 8 + (d & 7)] = f2h(ex[j] * rden);
      }
    }
  }
  __syncthreads();

  // ---- attn@v: wave = (hd, nh); head hd, e-cols nh*32..nh*32+31 ----
  int hd = w >> 1, nh = w & 1;
  const half8* AH = (const half8*)aswz[hd];
  half8 afa[4][2];
#pragma unroll
  for (int m2 = 0; m2 < 4; ++m2)
#pragma unroll
    for (int kk = 0; kk < 2; ++kk)
      afa[m2][kk] = AH[m2 * 128 + kk * 64 + lane];
  const half8* VH = (const half8*)vswz[hd];
  half8 bfv[2][2];
#pragma unroll
  for (int nt = 0; nt < 2; ++nt) {
    int n = nh * 32 + nt * 16 + nl;
#pragma unroll
    for (int kk = 0; kk < 2; ++kk) bfv[nt][kk] = VH[(kk * 64 + n) * 4 + q];
  }
  floatx4 oacc[4][2];
#pragma unroll
  for (int m2 = 0; m2 < 4; ++m2)
#pragma unroll
    for (int nt = 0; nt < 2; ++nt) oacc[m2][nt] = (floatx4){0.f, 0.f, 0.f, 0.f};
#pragma unroll
  for (int m2 = 0; m2 < 4; ++m2)
#pragma unroll
    for (int nt = 0; nt < 2; ++nt) {
      oacc[m2][nt] = __builtin_amdgcn_mfma_f32_16x16x32_f16(afa[m2][0], bfv[nt][0], oacc[m2][nt], 0, 0, 0);
      oacc[m2][nt] = __builtin_amdgcn_mfma_f32_16x16x32_f16(afa[m2][1], bfv[nt][1], oacc[m2][nt], 0, 0, 0);
    }

  // ---- cross-wave rowmax of O (each wave holds 32 of a row's 256 cols) ----
#pragma unroll
  for (int m2 = 0; m2 < 4; ++m2)
#pragma unroll
    for (int reg = 0; reg < 4; ++reg) {
      float pm = fmaxf(oacc[m2][0][reg], oacc[m2][1][reg]);
#pragma unroll
      for (int off = 8; off > 0; off >>= 1) pm = fmaxf(pm, __shfl_xor(pm, off));
      if (nl == 0) pmax[w][m2 * 16 + rb + reg] = pm;
    }
  __syncthreads();
  if (t < 64) {
    float m = pmax[0][t];
#pragma unroll
    for (int j = 1; j < 8; ++j) m = fmaxf(m, pmax[j][t]);
    Omax[t] = m;
  }
  __syncthreads();

  // ---- exp(O - rowmax) -> A-frag oswz (reuses xoswz region; all reads of
  //      xswz finished before the post-qkv barrier) ----
#pragma unroll
  for (int m2 = 0; m2 < 4; ++m2)
#pragma unroll
    for (int nt = 0; nt < 2; ++nt) {
      int c = hd * 64 + nh * 32 + nt * 16 + nl;
#pragma unroll
      for (int reg = 0; reg < 4; ++reg) {
        float e = __expf(oacc[m2][nt][reg] - Omax[m2 * 16 + rb + reg]);
        xoswz[m2][(c >> 5) * 512 + ((c >> 3) & 3) * 128 + (rb + reg) * 8 + (c & 7)]
            = f2h(e);
      }
    }
  __syncthreads();

  // ---- o-linear MFMA: wave = (mt, hf) again; 16 rows x 128 cols ----
  const half8* OA = (const half8*)xoswz[mt];
  half8 af2[8];
#pragma unroll
  for (int kk = 0; kk < 8; ++kk) af2[kk] = OA[kk * 64 + lane];
  const half8* BO = (const half8*)EoS;
  floatx4 acc2[8];
#pragma unroll
  for (int nt = 0; nt < 8; ++nt) acc2[nt] = (floatx4){0.f, 0.f, 0.f, 0.f};
#pragma unroll
  for (int nt = 0; nt < 8; ++nt) {
    int n4 = (hf * 128 + nt * 16 + nl) * 4 + q;
#pragma unroll
    for (int kk = 0; kk < 8; ++kk)
      acc2[nt] = __builtin_amdgcn_mfma_f32_16x16x32_f16(af2[kk], BO[kk * 1024 + n4], acc2[nt], 0, 0, 0);
  }

  // ---- final epilogue: y = Omax + log(acc) + bo, directly in C-layout ----
  float MrO[4];
#pragma unroll
  for (int reg = 0; reg < 4; ++reg) MrO[reg] = Omax[mt * 16 + rb + reg];
#pragma unroll
  for (int nt = 0; nt < 8; ++nt) {
    int c = hf * 128 + nt * 16 + nl;
    float bov = bo[c];
#pragma unroll
    for (int reg = 0; reg < 4; ++reg) {
      int r = mt * 16 + rb + reg;
      y[(size_t)(b * 64 + r) * ED + c] = MrO[reg] + __logf(acc2[nt][reg]) + bov;
    }
  }
}

// ---------------------------------------------------------------------------
extern "C" void kernel_launch(void* const* d_in, const int* in_sizes, int n_in,
                              void* d_out, int out_size, void* d_ws, size_t ws_size,
                              hipStream_t stream) {
  const float* x  = (const float*)d_in[0];
  const float* Wq = (const float*)d_in[1];
  const float* bq = (const float*)d_in[2];
  const float* Wk = (const float*)d_in[3];
  const float* bk = (const float*)d_in[4];
  const float* Wv = (const float*)d_in[5];
  const float* bv = (const float*)d_in[6];
  const float* Wo = (const float*)d_in[7];
  const float* bo = (const float*)d_in[8];
  float* y = (float*)d_out;

  // ws (bytes): EqS/EkS/EvS/EoS 128K each (total 512K)
  char* ws = (char*)d_ws;
  unsigned short* EqS = (unsigned short*)(ws);
  unsigned short* EkS = (unsigned short*)(ws + 131072);
  unsigned short* EvS = (unsigned short*)(ws + 262144);
  unsigned short* EoS = (unsigned short*)(ws + 393216);

  expT_swz_kernel<<<dim3(32, 4), 256, 0, stream>>>(Wq, Wk, Wv, Wo,
                                                   EqS, EkS, EvS, EoS);
  fused_attn_kernel<<<32, 512, 0, stream>>>(x, EqS, EkS, EvS, EoS,
                                            bq, bk, bv, bo, y);
}

// Round 4
// 95.950 us; speedup vs baseline: 1.1831x; 1.1831x over previous
//
#include <hip/hip_runtime.h>

// Problem dims (fixed by reference): B=32, S=64, E=256, H=4, D=64
constexpr int ED = 256;    // embedding dim

typedef _Float16 half8 __attribute__((ext_vector_type(8)));
typedef float floatx4 __attribute__((ext_vector_type(4)));

__device__ inline unsigned short f2h(float f) {   // fp32 -> fp16 bits (RNE)
  union { _Float16 h; unsigned short u; } c;
  c.h = (_Float16)f;
  return c.u;
}

// 8 contiguous fp32 -> fp16 exp() fragment (B-frag slice for one kk):
// frag[j] = (fp16) exp(p[j]),  p 32B-aligned.
__device__ inline half8 expfrag(const float* __restrict__ p) {
  float4 a = *(const float4*)p;
  float4 b = *(const float4*)(p + 4);
  half8 r;
  r[0] = (_Float16)__expf(a.x); r[1] = (_Float16)__expf(a.y);
  r[2] = (_Float16)__expf(a.z); r[3] = (_Float16)__expf(a.w);
  r[4] = (_Float16)__expf(b.x); r[5] = (_Float16)__expf(b.y);
  r[6] = (_Float16)__expf(b.z); r[7] = (_Float16)__expf(b.w);
  return r;
}

// ---------------------------------------------------------------------------
// Kernel 1: MFMA qkv. Block = 4 waves = M-tile 16 rows x one head (64 cols).
// grid 512 = 128 m-tiles x 4 heads (2 blocks/CU).
// B-fragments are computed INLINE from Wq/Wk/Wv (2x float4 load + 8 expf per
// fragment) instead of a prep kernel: lane needs exp(W[n][32kk+8q .. +7]),
// which is 32B contiguous. Deletes the prep launch + E-buffer round-trip.
// Epilogue: fused 64-wide softmax(q+k); writes attn in A-frag-swizzled fp16
// (AS) and v in B-frag-swizzled fp16 (VS).
// ---------------------------------------------------------------------------
__global__ __launch_bounds__(256, 2) void qkv_mfma_kernel(
    const float* __restrict__ x,
    const float* __restrict__ Wq, const float* __restrict__ Wk,
    const float* __restrict__ Wv,
    const float* __restrict__ bq, const float* __restrict__ bk,
    const float* __restrict__ bv,
    unsigned short* __restrict__ AS, unsigned short* __restrict__ VS)
{
  int t = threadIdx.x;
  int w = t >> 6, lane = t & 63;
  int mt = blockIdx.x >> 2, h = blockIdx.x & 3;
  int row0 = mt * 16;

  __shared__ unsigned short aswz[8 * 512];   // 8 KB fp16 A-frags [kk][q][m][jj]
  __shared__ float fbuf[3][16][65];          // ~12.5 KB (pad 65)
  __shared__ float Mrow[16];

  // --- issue x loads first ---
  float4 xv[4];
#pragma unroll
  for (int i = 0; i < 4; ++i)
    xv[i] = *(const float4*)&x[(size_t)(row0 + 4 * w + i) * ED + lane * 4];

  // --- B-fragments inline from W: n = h*64+w*16+(lane&15), q = lane>>4 ---
  int ncol = h * 64 + w * 16 + (lane & 15);
  int q8 = (lane >> 4) * 8;
  const float* pWq = Wq + (size_t)ncol * ED + q8;
  const float* pWk = Wk + (size_t)ncol * ED + q8;
  const float* pWv = Wv + (size_t)ncol * ED + q8;
  half8 bqf[8], bkf[8], bvf[8];
#pragma unroll
  for (int kk = 0; kk < 8; ++kk) {
    bqf[kk] = expfrag(pWq + 32 * kk);
    bkf[kk] = expfrag(pWk + 32 * kk);
    bvf[kk] = expfrag(pWv + 32 * kk);
  }

  // --- prologue: wave w stages rows 4w..4w+3 as fp16 A-fragments ---
#pragma unroll
  for (int i = 0; i < 4; ++i) {
    int r = 4 * w + i;
    float m = fmaxf(fmaxf(xv[i].x, xv[i].y), fmaxf(xv[i].z, xv[i].w));
#pragma unroll
    for (int off = 32; off > 0; off >>= 1) m = fmaxf(m, __shfl_xor(m, off));
    ushort4 pk;
    pk.x = f2h(__expf(xv[i].x - m));
    pk.y = f2h(__expf(xv[i].y - m));
    pk.z = f2h(__expf(xv[i].z - m));
    pk.w = f2h(__expf(xv[i].w - m));
    int k0 = lane * 4;                       // kk=k0>>5, q=(k0>>3)&3, jj=k0&7
    int idx = (k0 >> 5) * 512 + ((k0 >> 3) & 3) * 128 + r * 8 + (k0 & 7);
    *(ushort4*)&aswz[idx] = pk;
    if (lane == 0) Mrow[r] = m;
  }
  __syncthreads();

  // --- A fragments: lane-consecutive 16B chunks, conflict-free b128 ---
  half8 afrag[8];
#pragma unroll
  for (int kk = 0; kk < 8; ++kk)
    afrag[kk] = *(const half8*)&aswz[kk * 512 + lane * 8];

  // --- MFMA main loop: B frags already in registers ---
  floatx4 accq = {0.f, 0.f, 0.f, 0.f};
  floatx4 acck = {0.f, 0.f, 0.f, 0.f};
  floatx4 accv = {0.f, 0.f, 0.f, 0.f};
#pragma unroll
  for (int kk = 0; kk < 8; ++kk) {
    accq = __builtin_amdgcn_mfma_f32_16x16x32_f16(afrag[kk], bqf[kk], accq, 0, 0, 0);
    acck = __builtin_amdgcn_mfma_f32_16x16x32_f16(afrag[kk], bkf[kk], acck, 0, 0, 0);
    accv = __builtin_amdgcn_mfma_f32_16x16x32_f16(afrag[kk], bvf[kk], accv, 0, 0, 0);
  }

  // --- C frags -> LDS (D: col=lane&15, row=4*(lane>>4)+reg) ---
  {
    int c = w * 16 + (lane & 15);
    int rb = (lane >> 4) * 4;
#pragma unroll
    for (int reg = 0; reg < 4; ++reg) {
      fbuf[0][rb + reg][c] = accq[reg];
      fbuf[1][rb + reg][c] = acck[reg];
      fbuf[2][rb + reg][c] = accv[reg];
    }
  }
  __syncthreads();

  // --- epilogue: wave w owns rows 4w..4w+3; lane = col (d) within head ---
  int cg = h * 64 + lane;
  float bqv = bq[cg], bkv = bk[cg], bvv = bv[cg];
  int b = row0 >> 6;
  int mt16 = (row0 >> 4) & 3;
  size_t asBase = (size_t)(((b * 4 + mt16) * 4) + h) * 1024
                + (lane >> 5) * 512 + ((lane >> 3) & 3) * 128 + (lane & 7);
#pragma unroll
  for (int i = 0; i < 4; ++i) {
    int r = 4 * w + i;
    float Mr = Mrow[r];
    float qv = Mr + __logf(fbuf[0][r][lane]) + bqv;
    float kv = Mr + __logf(fbuf[1][r][lane]) + bkv;
    float vv = Mr + __logf(fbuf[2][r][lane]) + bvv;
    // v -> B-frag-swizzled VS: k = d = mt16*16 + r, n = cg
    int d = mt16 * 16 + r;
    VS[(size_t)(b * 2 + (d >> 5)) * 8192 + cg * 32 + ((d >> 3) & 3) * 8 + (d & 7)]
        = f2h(vv);
    // softmax of q+k over the 64-lane head segment
    float s = qv + kv;
    float sm = s;
#pragma unroll
    for (int off = 32; off > 0; off >>= 1) sm = fmaxf(sm, __shfl_xor(sm, off));
    float ex = __expf(s - sm);
    float den = ex;
#pragma unroll
    for (int off = 32; off > 0; off >>= 1) den += __shfl_xor(den, off);
    // attn -> A-frag-swizzled AS: m = r, k = lane
    AS[asBase + r * 8] = f2h(ex / den);
  }
}

// ---------------------------------------------------------------------------
// Kernel 2: fused MFMA attn@v + output tropical linear.
// grid 256 = (b, mt, half): block = 4 waves. Each block does the FULL
// attn@v (wave w = head w, 8 MFMAs — duplicated across the 2 halves) and
// full rowmax/exp, then the o-linear for its 128-col half only.
// BO fragments computed inline from Wo (issued at kernel start so the load
// latency hides under attn@v + rowmax phases).
// ---------------------------------------------------------------------------
__global__ __launch_bounds__(256, 2) void avo_mfma_kernel(
    const unsigned short* __restrict__ AS, const unsigned short* __restrict__ VS,
    const float* __restrict__ Wo, const float* __restrict__ bo,
    float* __restrict__ y)
{
  int t = threadIdx.x, w = t >> 6, lane = t & 63;
  int blk = blockIdx.x;
  int b = blk >> 3, mt = (blk >> 1) & 3, hf = blk & 1;
  int row0 = b * 64 + mt * 16;
  int q = lane >> 4, nl = lane & 15;

  __shared__ float obuf[16][260];            // 16.6 KB (pad 260)
  __shared__ unsigned short easwz[8 * 512];  // 8 KB
  __shared__ float Mrow[16];

  // ---- BO fragments inline from Wo, issued first (hide under attn@v):
  //      n = hf*128 + w*32 + nt*16 + nl; frag = exp(Wo[n][32kk+8q .. +7]) ----
  int q8 = q * 8;
  const float* pWo = Wo + (size_t)(hf * 128 + w * 32 + nl) * ED + q8;
  half8 bof[8][2];
#pragma unroll
  for (int nt = 0; nt < 2; ++nt)
#pragma unroll
    for (int kk = 0; kk < 8; ++kk)
      bof[kk][nt] = expfrag(pWo + (size_t)nt * 16 * ED + 32 * kk);

  // ---- attn@v (full 256 cols): wave w = head w ----
  const half8* AS8 = (const half8*)(AS + (size_t)(((b * 4 + mt) * 4) + w) * 1024);
  const half8* VS8 = (const half8*)VS;
  half8 af0 = AS8[lane], af1 = AS8[64 + lane];
  floatx4 acc[4];
#pragma unroll
  for (int nt = 0; nt < 4; ++nt) acc[nt] = (floatx4){0.f, 0.f, 0.f, 0.f};
#pragma unroll
  for (int nt = 0; nt < 4; ++nt) {
    int n = w * 64 + nt * 16 + nl;
    half8 b0 = VS8[(size_t)(b * 2 + 0) * 1024 + n * 4 + q];
    half8 b1 = VS8[(size_t)(b * 2 + 1) * 1024 + n * 4 + q];
    acc[nt] = __builtin_amdgcn_mfma_f32_16x16x32_f16(af0, b0, acc[nt], 0, 0, 0);
    acc[nt] = __builtin_amdgcn_mfma_f32_16x16x32_f16(af1, b1, acc[nt], 0, 0, 0);
  }
  int rb = q * 4;
#pragma unroll
  for (int nt = 0; nt < 4; ++nt)
#pragma unroll
    for (int reg = 0; reg < 4; ++reg)
      obuf[rb + reg][w * 64 + nt * 16 + nl] = acc[nt][reg];
  __syncthreads();

  // ---- rowmax + exp + A-frag swizzle for the o-linear (full row) ----
#pragma unroll
  for (int i = 0; i < 4; ++i) {
    int r = 4 * w + i;
    float4 o4 = *(const float4*)&obuf[r][lane * 4];
    float m = fmaxf(fmaxf(o4.x, o4.y), fmaxf(o4.z, o4.w));
#pragma unroll
    for (int off = 32; off > 0; off >>= 1) m = fmaxf(m, __shfl_xor(m, off));
    ushort4 pk;
    pk.x = f2h(__expf(o4.x - m));
    pk.y = f2h(__expf(o4.y - m));
    pk.z = f2h(__expf(o4.z - m));
    pk.w = f2h(__expf(o4.w - m));
    int k0 = lane * 4;
    int idx = (k0 >> 5) * 512 + ((k0 >> 3) & 3) * 128 + r * 8 + (k0 & 7);
    *(ushort4*)&easwz[idx] = pk;
    if (lane == 0) Mrow[r] = m;
  }
  __syncthreads();

  // ---- o-linear MFMA: this half's 128 cols; wave w -> 32 cols ----
  half8 af2[8];
#pragma unroll
  for (int kk = 0; kk < 8; ++kk)
    af2[kk] = *(const half8*)&easwz[kk * 512 + lane * 8];
  floatx4 acc2[2];
  acc2[0] = (floatx4){0.f, 0.f, 0.f, 0.f};
  acc2[1] = (floatx4){0.f, 0.f, 0.f, 0.f};
#pragma unroll
  for (int kk = 0; kk < 8; ++kk) {
#pragma unroll
    for (int nt = 0; nt < 2; ++nt)
      acc2[nt] = __builtin_amdgcn_mfma_f32_16x16x32_f16(
          af2[kk], bof[kk][nt], acc2[nt], 0, 0, 0);
  }
#pragma unroll
  for (int nt = 0; nt < 2; ++nt)
#pragma unroll
    for (int reg = 0; reg < 4; ++reg)
      obuf[rb + reg][hf * 128 + w * 32 + nt * 16 + nl] = acc2[nt][reg];
  __syncthreads();

  // ---- epilogue: log + bias, float2 stores over this half's 128 cols ----
  int c0 = hf * 128 + lane * 2;
  float2 bo2 = *(const float2*)&bo[c0];
#pragma unroll
  for (int i = 0; i < 4; ++i) {
    int r = 4 * w + i;
    float2 f2 = *(const float2*)&obuf[r][c0];
    float M = Mrow[r];
    float2 y2;
    y2.x = M + __logf(f2.x) + bo2.x;
    y2.y = M + __logf(f2.y) + bo2.y;
    *(float2*)&y[(size_t)(row0 + r) * ED + c0] = y2;
  }
}

// ---------------------------------------------------------------------------
extern "C" void kernel_launch(void* const* d_in, const int* in_sizes, int n_in,
                              void* d_out, int out_size, void* d_ws, size_t ws_size,
                              hipStream_t stream) {
  const float* x  = (const float*)d_in[0];
  const float* Wq = (const float*)d_in[1];
  const float* bq = (const float*)d_in[2];
  const float* Wk = (const float*)d_in[3];
  const float* bk = (const float*)d_in[4];
  const float* Wv = (const float*)d_in[5];
  const float* bv = (const float*)d_in[6];
  const float* Wo = (const float*)d_in[7];
  const float* bo = (const float*)d_in[8];
  float* y = (float*)d_out;

  // ws (bytes): AS 1M | VS 1M
  char* ws = (char*)d_ws;
  unsigned short* AS = (unsigned short*)(ws);
  unsigned short* VS = (unsigned short*)(ws + 1048576);

  qkv_mfma_kernel<<<512, 256, 0, stream>>>(x, Wq, Wk, Wv, bq, bk, bv, AS, VS);
  avo_mfma_kernel<<<256, 256, 0, stream>>>(AS, VS, Wo, bo, y);
}